// Round 14
// baseline (94.987 us; speedup 1.0000x reference)
//
#include <hip/hip_runtime.h>
#include <hip/hip_bf16.h>

#define B_    128
#define H_    256
#define WI_   256
#define CIN   8
#define COUT  8
#define SS    32
#define RST   (WI_*CIN)     // 2048 f32 per input row
#define OST   (WI_*COUT)    // 2048 f32 per output row
#define LROW  2064          // 258 cols x 8 ci bf16: halo col -1 @0, col 256 @2056

typedef __attribute__((ext_vector_type(8))) short bh8;   // 8 bf16 = MFMA A/B frag
typedef __attribute__((ext_vector_type(4))) float f4;    // MFMA C/D frag

static __device__ __forceinline__ unsigned short f2bf(float f) {
    union { __hip_bfloat16 h; unsigned short u; } c;
    c.h = __float2bfloat16(f);
    return c.u;
}

// cvt 8 f32 -> 8 bf16, one ds_write_b128
static __device__ __forceinline__ void wr8(__hip_bfloat16* dst, float4 a, float4 c) {
    union { bh8 v; unsigned short u[8]; } r;
    r.u[0]=f2bf(a.x); r.u[1]=f2bf(a.y); r.u[2]=f2bf(a.z); r.u[3]=f2bf(a.w);
    r.u[4]=f2bf(c.x); r.u[5]=f2bf(c.y); r.u[6]=f2bf(c.z); r.u[7]=f2bf(c.w);
    *(bh8*)dst = r.v;
}

// Block = one sample x 32-row strip x full 256-col row.
// LDS ring: 4 slabs, each one X row as bf16 with zero halo cols (-1, 256).
// Staging: reg path (load f32 -> cvt -> ds_write) with distance-1 ping-pong
// G regs and counted vmcnt. Inner loop per subtile: ds_read_b128 -> 3 MFMA,
// no VALU, no masks (edge cols and k-pad lanes read the zero halo).
__global__ __launch_bounds__(256, 4)
void conv_mfma_kernel(const float* __restrict__ X,
                      const float* __restrict__ Wt,
                      const float* __restrict__ bias,
                      const float* __restrict__ Werr,
                      const float* __restrict__ Berr,
                      float* __restrict__ out)
{
    __shared__ __align__(16) __hip_bfloat16 xs[4][LROW];  // 16.5 KB ring
    __shared__ float wlds[576];                           // noisy weights

    const int tid = threadIdx.x;
    const int b   = blockIdx.y;
    const int rs  = blockIdx.x * SS;

    {   // noisy weights, transposed [khkw][cout][cin]
        const float* we = Werr + (size_t)b * 576;
        for (int i = tid; i < 576; i += 256) {
            const int khkw = i >> 6, ci = (i >> 3) & 7, co = i & 7;
            wlds[(khkw * 8 + co) * 8 + ci] = Wt[i] * we[i];
        }
    }
    if (tid < 8) {                        // zero halo cols of all 4 slots (stay zero)
        const bh8 z = {0,0,0,0,0,0,0,0};
        *(bh8*)&xs[tid >> 1][(tid & 1) ? 2056 : 0] = z;
    }

    const int lane = tid & 63, wid = tid >> 6;
    const int p = lane & 15, g = lane >> 4;

    f4 biasF = {0.f, 0.f, 0.f, 0.f};
    if (g < 2) {
        #pragma unroll
        for (int r = 0; r < 4; ++r) {
            const int co = g * 4 + r;
            biasF[r] = bias[co] * Berr[(size_t)b * COUT + co];
        }
    }
    __syncthreads();

    // weight fragments (A operand, M=cout): zero for p>=8 or g==3
    bh8 Wf0, Wf1, Wf2;
    {
        #pragma unroll
        for (int kh = 0; kh < 3; ++kh) {
            union { bh8 v; unsigned short u[8]; } r;
            #pragma unroll
            for (int j = 0; j < 8; ++j) r.u[j] = 0;
            if (p < 8 && g < 3) {
                const float* ptr = &wlds[((kh * 3 + g) * 8 + p) * 8];
                const float4 lo = *(const float4*)ptr;
                const float4 hi = *(const float4*)(ptr + 4);
                r.u[0]=f2bf(lo.x); r.u[1]=f2bf(lo.y); r.u[2]=f2bf(lo.z); r.u[3]=f2bf(lo.w);
                r.u[4]=f2bf(hi.x); r.u[5]=f2bf(hi.y); r.u[6]=f2bf(hi.z); r.u[7]=f2bf(hi.w);
            }
            if (kh == 0) Wf0 = r.v; else if (kh == 1) Wf1 = r.v; else Wf2 = r.v;
        }
    }

    // per-subtile LDS element offsets (per-thread constants).
    // frag col = wid*64 + s*16 + p + g - 1; LDS index (1+col)*8.
    // g==3 (k-pad) -> offset 0 = zero halo. edge cols land on halos too.
    const int coff0 = (g == 3) ? 0 : (wid * 64 +  0 + p + g) * 8;
    const int coff1 = (g == 3) ? 0 : (wid * 64 + 16 + p + g) * 8;
    const int coff2 = (g == 3) ? 0 : (wid * 64 + 32 + p + g) * 8;
    const int coff3 = (g == 3) ? 0 : (wid * 64 + 48 + p + g) * 8;

    const float* __restrict__ xb = X   + (size_t)b * H_ * RST;
    float*       __restrict__ ob = out + (size_t)b * H_ * OST;
    const float4 z4 = make_float4(0.f, 0.f, 0.f, 0.f);

    // prologue: rows rs-1, rs, rs+1 -> slots 0,1,2 (thread t = col t)
    {
        float4 a, c;
        if (rs > 0) {
            const float* gp = xb + (size_t)(rs - 1) * RST + tid * CIN;
            a = *(const float4*)gp; c = *(const float4*)(gp + 4);
        } else { a = z4; c = z4; }
        wr8(&xs[0][(1 + tid) * 8], a, c);
        const float* gp1 = xb + (size_t)rs * RST + tid * CIN;
        wr8(&xs[1][(1 + tid) * 8], *(const float4*)gp1, *(const float4*)(gp1 + 4));
        const float* gp2 = xb + (size_t)(rs + 1) * RST + tid * CIN;
        wr8(&xs[2][(1 + tid) * 8], *(const float4*)gp2, *(const float4*)(gp2 + 4));
    }
    __syncthreads();

    // prefetch row rs+2 into Gb (after the barrier so it isn't drained)
    float4 Ga0, Ga1, Gb0, Gb1;
    {
        const float* gp = xb + (size_t)(rs + 2) * RST + tid * CIN;
        Gb0 = *(const float4*)gp; Gb1 = *(const float4*)(gp + 4);
    }
    int srow = rs + 3;                    // next row to load
    int soff = (rs * WI_ + wid * 64 + p) * COUT + g * 4;

    f4 P1_0=biasF, P2_0=biasF, P1_1=biasF, P2_1=biasF;
    f4 P1_2=biasF, P2_2=biasF, P1_3=biasF, P2_3=biasF;
    f4 dn0, dn1, dn2, dn3;

#define SUB(SLOT, CO, P1N, P2N, DN) do {                                       \
    const bh8 xf_ = *(const bh8*)&xs[SLOT][CO];                                \
    DN  = __builtin_amdgcn_mfma_f32_16x16x32_bf16(Wf2, xf_, P1N, 0,0,0);       \
    P1N = __builtin_amdgcn_mfma_f32_16x16x32_bf16(Wf1, xf_, P2N, 0,0,0);       \
    P2N = __builtin_amdgcn_mfma_f32_16x16x32_bf16(Wf0, xf_, biasF, 0,0,0);     \
} while (0)

#define STORES do {                                                            \
    if (lane < 32) {                                                           \
        __builtin_nontemporal_store(dn0, (f4*)(ob + soff));                    \
        __builtin_nontemporal_store(dn1, (f4*)(ob + soff + 128));              \
        __builtin_nontemporal_store(dn2, (f4*)(ob + soff + 256));              \
        __builtin_nontemporal_store(dn3, (f4*)(ob + soff + 384));              \
    }                                                                          \
    soff += OST;                                                               \
} while (0)

// order: [loads GN] | [4x SUB] [stores] | vmcnt(VM) [cvt+write GO] lgkm barrier
#define STEP(VM, SLOT, WSLOT, SP, DL, GN0, GN1, GO0, GO1) do {                 \
    if (DL) {                                                                  \
        const int lr_ = srow < H_ ? srow : H_ - 1;                             \
        const float* gp_ = xb + (size_t)lr_ * RST + tid * CIN;                 \
        GN0 = *(const float4*)gp_; GN1 = *(const float4*)(gp_ + 4);            \
        ++srow;                                                                \
    }                                                                          \
    __builtin_amdgcn_sched_barrier(0);                                         \
    SUB(SLOT, coff0, P1_0, P2_0, dn0);                                         \
    SUB(SLOT, coff1, P1_1, P2_1, dn1);                                         \
    SUB(SLOT, coff2, P1_2, P2_2, dn2);                                         \
    SUB(SLOT, coff3, P1_3, P2_3, dn3);                                         \
    if (SP) STORES;                                                            \
    __builtin_amdgcn_sched_barrier(0);                                         \
    asm volatile("s_waitcnt vmcnt(" #VM ")" ::: "memory");                     \
    wr8(&xs[WSLOT][(1 + tid) * 8], GO0, GO1);                                  \
    asm volatile("s_waitcnt lgkmcnt(0)" ::: "memory");                         \
    __builtin_amdgcn_s_barrier();                                              \
} while (0)

    // step i: computes input row rs-1+i from slot i&3; writes GO (row rs+2+i)
    // into slot (i+3)&3; loads GN = row rs+3+i. stores out row rs+i-2 (i>=2).
    STEP(2,  0, 3, 0, 1, Ga0, Ga1, Gb0, Gb1);   // i=0
    STEP(2,  1, 0, 0, 1, Gb0, Gb1, Ga0, Ga1);   // i=1
    STEP(6,  2, 1, 1, 1, Ga0, Ga1, Gb0, Gb1);   // i=2
    STEP(10, 3, 2, 1, 1, Gb0, Gb1, Ga0, Ga1);   // i=3
    #pragma unroll 1
    for (int it = 0; it < 6; ++it) {            // i = 4..27
        STEP(10, 0, 3, 1, 1, Ga0, Ga1, Gb0, Gb1);
        STEP(10, 1, 0, 1, 1, Gb0, Gb1, Ga0, Ga1);
        STEP(10, 2, 1, 1, 1, Ga0, Ga1, Gb0, Gb1);
        STEP(10, 3, 2, 1, 1, Gb0, Gb1, Ga0, Ga1);
    }
    STEP(10, 0, 3, 1, 1, Ga0, Ga1, Gb0, Gb1);   // i=28
    STEP(10, 1, 0, 1, 1, Gb0, Gb1, Ga0, Ga1);   // i=29 (loads row rs+32 -> Gb)
    STEP(8,  2, 1, 1, 0, Ga0, Ga1, Gb0, Gb1);   // i=30: write row rs+32 -> slot 1

    // i=31, 32: no loads/writes/barriers needed (all slots stable)
    SUB(3, coff0, P1_0, P2_0, dn0);
    SUB(3, coff1, P1_1, P2_1, dn1);
    SUB(3, coff2, P1_2, P2_2, dn2);
    SUB(3, coff3, P1_3, P2_3, dn3);
    STORES;                                     // out rs+29
    SUB(0, coff0, P1_0, P2_0, dn0);
    SUB(0, coff1, P1_1, P2_1, dn1);
    SUB(0, coff2, P1_2, P2_2, dn2);
    SUB(0, coff3, P1_3, P2_3, dn3);
    STORES;                                     // out rs+30

    // out row rs+31: kh=2 term from input row rs+32 (slot 1); bottom: zero pad
    if (rs + SS < H_) {
        const bh8 e0 = *(const bh8*)&xs[1][coff0];
        const bh8 e1 = *(const bh8*)&xs[1][coff1];
        const bh8 e2 = *(const bh8*)&xs[1][coff2];
        const bh8 e3 = *(const bh8*)&xs[1][coff3];
        P1_0 = __builtin_amdgcn_mfma_f32_16x16x32_bf16(Wf2, e0, P1_0, 0,0,0);
        P1_1 = __builtin_amdgcn_mfma_f32_16x16x32_bf16(Wf2, e1, P1_1, 0,0,0);
        P1_2 = __builtin_amdgcn_mfma_f32_16x16x32_bf16(Wf2, e2, P1_2, 0,0,0);
        P1_3 = __builtin_amdgcn_mfma_f32_16x16x32_bf16(Wf2, e3, P1_3, 0,0,0);
    }
    if (lane < 32) {
        __builtin_nontemporal_store(P1_0, (f4*)(ob + soff));
        __builtin_nontemporal_store(P1_1, (f4*)(ob + soff + 128));
        __builtin_nontemporal_store(P1_2, (f4*)(ob + soff + 256));
        __builtin_nontemporal_store(P1_3, (f4*)(ob + soff + 384));
    }

#undef STEP
#undef STORES
#undef SUB
}

extern "C" void kernel_launch(void* const* d_in, const int* in_sizes, int n_in,
                              void* d_out, int out_size, void* d_ws, size_t ws_size,
                              hipStream_t stream) {
    const float* X    = (const float*)d_in[0];
    const float* Wt   = (const float*)d_in[1];
    const float* bias = (const float*)d_in[2];
    const float* Werr = (const float*)d_in[3];
    const float* Berr = (const float*)d_in[4];
    float* out = (float*)d_out;

    dim3 grid(H_ / SS, B_);               // (8, 128) = 1024 blocks
    conv_mfma_kernel<<<grid, 256, 0, stream>>>(X, Wt, bias, Werr, Berr, out);
}